// Round 2
// baseline (3315.690 us; speedup 1.0000x reference)
//
#include <hip/hip_runtime.h>
#include <math.h>

#define B_  32
#define S_  1024
#define D_  256
#define DS_ 64
#define M_  3
#define MD_ 192   // M*DS

// lgkmcnt-only barrier: LDS visibility without draining vmcnt (keeps global
// prefetch loads / result stores in flight across recurrence steps).
#define BAR_LGKM() asm volatile("s_waitcnt lgkmcnt(0)\n\ts_barrier" ::: "memory")

__device__ __forceinline__ float rl_f32(float v, int lane) {
    return __uint_as_float(__builtin_amdgcn_readlane(__float_as_uint(v), lane));
}

// ---------------------------------------------------------------------------
// Kernel 1: xp[b][t][m*64+d] = Xb[m][d] + sum_k XW[m][d][k] * x_m[b][t][k]
// (unchanged from R1 — known correct; optimize after k2 shrinks)
// ---------------------------------------------------------------------------
__global__ __launch_bounds__(256, 2)
void k1_xproj(const float* __restrict__ xa, const float* __restrict__ xv,
              const float* __restrict__ xl, const float* __restrict__ XW,
              const float* __restrict__ Xb, float* __restrict__ xp)
{
    const int m  = blockIdx.z;
    const int b  = blockIdx.y;
    const int t0 = blockIdx.x * 128;
    const float* __restrict__ xm = (m == 0) ? xa : ((m == 1) ? xv : xl);
    const int tid = threadIdx.x;
    const int q = tid >> 6;
    const int d = tid & 63;

    __shared__ __align__(16) float xs[4][256];
    __shared__ float part[4][4][64];

    float w[64];
    {
        const float4* src = reinterpret_cast<const float4*>(XW + ((m * 64 + d) * 256 + q * 64));
        #pragma unroll
        for (int e4 = 0; e4 < 16; ++e4) {
            float4 v = src[e4];
            w[e4 * 4 + 0] = v.x; w[e4 * 4 + 1] = v.y;
            w[e4 * 4 + 2] = v.z; w[e4 * 4 + 3] = v.w;
        }
    }
    const float xbv = Xb[m * 64 + d];

    for (int g = 0; g < 32; ++g) {
        const int tb = t0 + g * 4;
        {
            const float* src = xm + ((size_t)b * S_ + tb) * D_;
            #pragma unroll
            for (int r = 0; r < 4; ++r)
                xs[r][tid] = src[r * 256 + tid];
        }
        __syncthreads();
        #pragma unroll
        for (int tt = 0; tt < 4; ++tt) {
            const float4* xq = reinterpret_cast<const float4*>(&xs[tt][q * 64]);
            float a0 = 0.f, a1 = 0.f, a2 = 0.f, a3 = 0.f;
            #pragma unroll
            for (int e4 = 0; e4 < 16; ++e4) {
                float4 hv = xq[e4];
                a0 += w[e4 * 4 + 0] * hv.x; a1 += w[e4 * 4 + 1] * hv.y;
                a2 += w[e4 * 4 + 2] * hv.z; a3 += w[e4 * 4 + 3] * hv.w;
            }
            part[tt][q][d] = (a0 + a1) + (a2 + a3);
        }
        __syncthreads();
        {
            const int tt = q;
            float ssum = part[tt][0][d] + part[tt][1][d] + part[tt][2][d] + part[tt][3][d] + xbv;
            xp[((size_t)b * S_ + tb + tt) * MD_ + m * 64 + d] = ssum;
        }
    }
}

// ---------------------------------------------------------------------------
// Kernel 2 v2: recurrence. 32 blocks (one per b) x 768 threads (12 waves).
//   waves 0..8  (w=m*3+s): lane d computes part[m][s][d] = Wrow(64) . h_s(64)
//        Wrow = (s==m ? HW[m,d,:] : CW[m,s,d,:])   -> 64 regs/lane (no spill)
//   waves 9..11 (g=w-9):   lane j computes gate partial W1[j, g*64:+64] . h_g
//   wave 9 then does the serial gate tail: z=tanh(sum+b1), raw=W2@z+b2
//        (W2 transposed in LDS, z broadcast by readlane), softmax -> attn LDS
//   owner waves (s==m) combine with attn, silu, write h (double-buffered LDS)
// h broadcast = v_readlane (VALU only). 3 lgkm-only barriers/step.
// xp prefetched 1 step ahead; hbuf stores batched every 4 steps.
// ---------------------------------------------------------------------------
__global__ __launch_bounds__(768, 1)
void k2_recur(const float* __restrict__ xp, float* __restrict__ hbuf,
              const float* __restrict__ HW, const float* __restrict__ Hb,
              const float* __restrict__ CW, const float* __restrict__ W1,
              const float* __restrict__ b1, const float* __restrict__ W2,
              const float* __restrict__ b2)
{
    const int b    = blockIdx.x;
    const int tid  = threadIdx.x;
    const int w    = tid >> 6;
    const int lane = tid & 63;

    const bool is_su    = (w < 9);
    const int  m        = is_su ? (w / 3) : 0;
    const int  s        = is_su ? (w % 3) : (w - 9);   // su: src seg; gate: seg g
    const bool is_owner = is_su && (s == m);
    const bool is_tail  = (w == 9);

    __shared__ __align__(16) float hds[2][MD_];
    __shared__ float parts[12][64];
    __shared__ float attnsh[9];
    __shared__ float w2t[64 * 9 + 64];   // transposed W2 [k][j], padded

    // ---- init ----
    for (int idx = tid; idx < 576; idx += 768) {
        int k = idx / 9, j = idx % 9;
        w2t[k * 9 + j] = W2[j * 64 + k];
    }
    if (tid < MD_) hds[0][tid] = 0.f;

    // 64 weights per lane — small enough to be truly register-resident
    float wk[64];
    {
        const float* base;
        if (is_su) base = (s == m) ? (HW + (m * 64 + lane) * 64)
                                   : (CW + (((m * 3 + s) * 64) + lane) * 64);
        else       base = W1 + lane * MD_ + s * 64;
        const float4* src = reinterpret_cast<const float4*>(base);
        #pragma unroll
        for (int e4 = 0; e4 < 16; ++e4) {
            float4 v = src[e4];
            wk[e4 * 4 + 0] = v.x; wk[e4 * 4 + 1] = v.y;
            wk[e4 * 4 + 2] = v.z; wk[e4 * 4 + 3] = v.w;
        }
    }

    const float hbv = is_owner ? Hb[m * 64 + lane] : 0.f;
    const float b1v = is_tail  ? b1[lane] : 0.f;
    const float b2v = (is_tail && lane < 9) ? b2[lane] : 0.f;

    const int s1 = (m + 1) % 3, s2 = (m + 2) % 3;

    float xnext = is_owner ? xp[((size_t)b * S_) * MD_ + m * 64 + lane] : 0.f;
    float hist0 = 0.f, hist1 = 0.f, hist2 = 0.f, hist3 = 0.f;

    __syncthreads();

    for (int t = 0; t < S_; ++t) {
        const int cur = t & 1, nxt = cur ^ 1;
        const float xv = xnext;
        if (is_owner && (t + 1 < S_))
            xnext = xp[((size_t)b * S_ + t + 1) * MD_ + m * 64 + lane];

        // ---- phase A: all 12 waves compute their 64-long partial dot ----
        float hreg = hds[cur][s * 64 + lane];
        float a0 = 0.f, a1 = 0.f, a2 = 0.f, a3 = 0.f;
        #pragma unroll
        for (int k4 = 0; k4 < 16; ++k4) {
            a0 += wk[k4 * 4 + 0] * rl_f32(hreg, k4 * 4 + 0);
            a1 += wk[k4 * 4 + 1] * rl_f32(hreg, k4 * 4 + 1);
            a2 += wk[k4 * 4 + 2] * rl_f32(hreg, k4 * 4 + 2);
            a3 += wk[k4 * 4 + 3] * rl_f32(hreg, k4 * 4 + 3);
        }
        const float acc = (a0 + a1) + (a2 + a3);
        parts[w][lane] = acc;
        BAR_LGKM();   // partials visible

        // ---- gate tail (wave 9 only) ----
        if (is_tail) {
            float z = tanhf(b1v + parts[9][lane] + parts[10][lane] + parts[11][lane]);
            float r0 = 0.f, r1 = 0.f, r2 = 0.f, r3 = 0.f;
            #pragma unroll
            for (int k = 0; k < 64; k += 4) {
                r0 += w2t[(k + 0) * 9 + lane] * rl_f32(z, k + 0);
                r1 += w2t[(k + 1) * 9 + lane] * rl_f32(z, k + 1);
                r2 += w2t[(k + 2) * 9 + lane] * rl_f32(z, k + 2);
                r3 += w2t[(k + 3) * 9 + lane] * rl_f32(z, k + 3);
            }
            float rawv = b2v + (r0 + r1) + (r2 + r3);
            // broadcast the 9 raw values, softmax rows uniformly in-wave
            float q0 = rl_f32(rawv, 0), q1 = rl_f32(rawv, 1), q2 = rl_f32(rawv, 2);
            float q3 = rl_f32(rawv, 3), q4 = rl_f32(rawv, 4), q5 = rl_f32(rawv, 5);
            float q6 = rl_f32(rawv, 6), q7 = rl_f32(rawv, 7), q8 = rl_f32(rawv, 8);
            float mx0 = fmaxf(q0, fmaxf(q1, q2));
            float mx1 = fmaxf(q3, fmaxf(q4, q5));
            float mx2 = fmaxf(q6, fmaxf(q7, q8));
            float e0 = expf(q0 - mx0), e1 = expf(q1 - mx0), e2 = expf(q2 - mx0);
            float e3 = expf(q3 - mx1), e4 = expf(q4 - mx1), e5 = expf(q5 - mx1);
            float e6 = expf(q6 - mx2), e7 = expf(q7 - mx2), e8 = expf(q8 - mx2);
            float i0 = 1.f / (e0 + e1 + e2);
            float i1 = 1.f / (e3 + e4 + e5);
            float i2 = 1.f / (e6 + e7 + e8);
            if (lane < 9) {
                float av;
                switch (lane) {
                    case 0: av = e0 * i0; break;
                    case 1: av = e1 * i0; break;
                    case 2: av = e2 * i0; break;
                    case 3: av = e3 * i1; break;
                    case 4: av = e4 * i1; break;
                    case 5: av = e5 * i1; break;
                    case 6: av = e6 * i2; break;
                    case 7: av = e7 * i2; break;
                    default: av = e8 * i2; break;
                }
                attnsh[lane] = av;
            }
        }
        BAR_LGKM();   // attn visible

        // ---- owner combine + state update ----
        if (is_owner) {
            float p1  = parts[m * 3 + s1][lane];
            float p2  = parts[m * 3 + s2][lane];
            float a1v = attnsh[m * 3 + s1];
            float a2v = attnsh[m * 3 + s2];
            float suv = xv + hbv + acc + a1v * p1 + a2v * p2;
            float hn  = suv / (1.f + expf(-suv));
            hds[nxt][m * 64 + lane] = hn;
            // batch global stores (4 steps) so per-step vmcnt waits see loads only
            if      ((t & 3) == 0) hist0 = hn;
            else if ((t & 3) == 1) hist1 = hn;
            else if ((t & 3) == 2) hist2 = hn;
            else {
                hist3 = hn;
                float* dst = hbuf + ((size_t)b * S_ + (t - 3)) * MD_ + m * 64 + lane;
                dst[0 * MD_] = hist0; dst[1 * MD_] = hist1;
                dst[2 * MD_] = hist2; dst[3 * MD_] = hist3;
            }
        }
        BAR_LGKM();   // h_new visible
    }
}

// ---------------------------------------------------------------------------
// Kernel 3: out = LayerNorm(Ob + OW@h + x)   (unchanged from R1)
// ---------------------------------------------------------------------------
__global__ __launch_bounds__(256, 2)
void k3_out(const float* __restrict__ xa, const float* __restrict__ xv,
            const float* __restrict__ xl, const float* __restrict__ hbuf,
            const float* __restrict__ OW, const float* __restrict__ Ob,
            const float* __restrict__ lng, const float* __restrict__ lnb,
            float* __restrict__ out)
{
    const int m  = blockIdx.z;
    const int b  = blockIdx.y;
    const int t0 = blockIdx.x * 128;
    const float* __restrict__ xm = (m == 0) ? xa : ((m == 1) ? xv : xl);
    const int k    = threadIdx.x;
    const int wv   = k >> 6;
    const int lane = k & 63;

    __shared__ __align__(16) float hs[4 * 64];
    __shared__ float psum[16], qsum[16];

    float ow[64];
    {
        const float4* src = reinterpret_cast<const float4*>(OW + (m * D_ + k) * DS_);
        #pragma unroll
        for (int e4 = 0; e4 < 16; ++e4) {
            float4 v = src[e4];
            ow[e4 * 4 + 0] = v.x; ow[e4 * 4 + 1] = v.y;
            ow[e4 * 4 + 2] = v.z; ow[e4 * 4 + 3] = v.w;
        }
    }
    const float obv = Ob[m * D_ + k];
    const float gv  = lng[m * D_ + k];
    const float bv  = lnb[m * D_ + k];

    for (int g = 0; g < 32; ++g) {
        const int tb = t0 + g * 4;
        hs[k] = hbuf[((size_t)b * S_ + tb + (k >> 6)) * MD_ + m * 64 + (k & 63)];
        __syncthreads();

        float v[4];
        #pragma unroll
        for (int tt = 0; tt < 4; ++tt) {
            const float4* h4 = reinterpret_cast<const float4*>(&hs[tt * 64]);
            float a0 = 0.f, a1 = 0.f, a2 = 0.f, a3 = 0.f;
            #pragma unroll
            for (int e4 = 0; e4 < 16; ++e4) {
                float4 hv = h4[e4];
                a0 += ow[e4 * 4 + 0] * hv.x; a1 += ow[e4 * 4 + 1] * hv.y;
                a2 += ow[e4 * 4 + 2] * hv.z; a3 += ow[e4 * 4 + 3] * hv.w;
            }
            float y = obv + (a0 + a1) + (a2 + a3);
            v[tt] = y + xm[((size_t)b * S_ + tb + tt) * D_ + k];
        }

        float sarr[4], qarr[4];
        #pragma unroll
        for (int tt = 0; tt < 4; ++tt) { sarr[tt] = v[tt]; qarr[tt] = v[tt] * v[tt]; }
        #pragma unroll
        for (int off = 32; off >= 1; off >>= 1) {
            #pragma unroll
            for (int tt = 0; tt < 4; ++tt) {
                sarr[tt] += __shfl_down(sarr[tt], off);
                qarr[tt] += __shfl_down(qarr[tt], off);
            }
        }
        if (lane == 0) {
            #pragma unroll
            for (int tt = 0; tt < 4; ++tt) { psum[wv * 4 + tt] = sarr[tt]; qsum[wv * 4 + tt] = qarr[tt]; }
        }
        __syncthreads();

        #pragma unroll
        for (int tt = 0; tt < 4; ++tt) {
            float ss = psum[0 + tt] + psum[4 + tt] + psum[8 + tt] + psum[12 + tt];
            float qq = qsum[0 + tt] + qsum[4 + tt] + qsum[8 + tt] + qsum[12 + tt];
            float mu  = ss * (1.f / 256.f);
            float var = qq * (1.f / 256.f) - mu * mu;
            float rs  = rsqrtf(var + 1e-5f);
            out[(size_t)m * ((size_t)B_ * S_ * D_) + ((size_t)b * S_ + tb + tt) * D_ + k]
                = (v[tt] - mu) * rs * gv + bv;
        }
    }
}

extern "C" void kernel_launch(void* const* d_in, const int* in_sizes, int n_in,
                              void* d_out, int out_size, void* d_ws, size_t ws_size,
                              hipStream_t stream)
{
    const float* xa  = (const float*)d_in[0];
    const float* xv  = (const float*)d_in[1];
    const float* xl  = (const float*)d_in[2];
    const float* XW  = (const float*)d_in[3];
    const float* Xb  = (const float*)d_in[4];
    const float* HW  = (const float*)d_in[5];
    const float* Hb  = (const float*)d_in[6];
    const float* OW  = (const float*)d_in[7];
    const float* Ob  = (const float*)d_in[8];
    const float* CW  = (const float*)d_in[9];
    const float* W1  = (const float*)d_in[10];
    const float* b1  = (const float*)d_in[11];
    const float* W2  = (const float*)d_in[12];
    const float* b2  = (const float*)d_in[13];
    const float* lng = (const float*)d_in[14];
    const float* lnb = (const float*)d_in[15];
    float* out = (float*)d_out;

    float* xp = (float*)d_ws;                          // [B][S][192]
    float* hb = xp + (size_t)B_ * S_ * MD_;            // [B][S][192]

    k1_xproj<<<dim3(8, 32, 3), 256, 0, stream>>>(xa, xv, xl, XW, Xb, xp);
    k2_recur<<<dim3(32), 768, 0, stream>>>(xp, hb, HW, Hb, CW, W1, b1, W2, b2);
    k3_out  <<<dim3(8, 32, 3), 256, 0, stream>>>(xa, xv, xl, hb, OW, Ob, lng, lnb, out);
}

// Round 3
// 2590.877 us; speedup vs baseline: 1.2798x; 1.2798x over previous
//
#include <hip/hip_runtime.h>
#include <math.h>

#define B_  32
#define S_  1024
#define D_  256
#define DS_ 64
#define M_  3
#define MD_ 192   // M*DS

// lgkmcnt-only barrier: LDS visibility without draining vmcnt (keeps global
// prefetch loads / result stores in flight across recurrence steps).
#define BAR_LGKM() asm volatile("s_waitcnt lgkmcnt(0)\n\ts_barrier" ::: "memory")

__device__ __forceinline__ float rl_f32(float v, int lane) {
    return __uint_as_float(__builtin_amdgcn_readlane(__float_as_uint(v), lane));
}

// ---- named-register weight block: 16 float4 = 64 floats, NO arrays --------
#define DECL_W16(src) \
    const float4 W00 = (src)[0],  W01 = (src)[1],  W02 = (src)[2],  W03 = (src)[3],  \
                 W04 = (src)[4],  W05 = (src)[5],  W06 = (src)[6],  W07 = (src)[7],  \
                 W08 = (src)[8],  W09 = (src)[9],  W10 = (src)[10], W11 = (src)[11], \
                 W12 = (src)[12], W13 = (src)[13], W14 = (src)[14], W15 = (src)[15];

// dot of the 64 named weights with lanes of hreg (readlane broadcast)
#define DOT4_RL(Wv, k0) \
    a0 = fmaf(Wv.x, rl_f32(hreg, (k0) + 0), a0); \
    a1 = fmaf(Wv.y, rl_f32(hreg, (k0) + 1), a1); \
    a2 = fmaf(Wv.z, rl_f32(hreg, (k0) + 2), a2); \
    a3 = fmaf(Wv.w, rl_f32(hreg, (k0) + 3), a3);
#define DOT64_RL() \
    DOT4_RL(W00, 0)  DOT4_RL(W01, 4)  DOT4_RL(W02, 8)  DOT4_RL(W03, 12) \
    DOT4_RL(W04, 16) DOT4_RL(W05, 20) DOT4_RL(W06, 24) DOT4_RL(W07, 28) \
    DOT4_RL(W08, 32) DOT4_RL(W09, 36) DOT4_RL(W10, 40) DOT4_RL(W11, 44) \
    DOT4_RL(W12, 48) DOT4_RL(W13, 52) DOT4_RL(W14, 56) DOT4_RL(W15, 60)

// dot of the 64 named weights with a float4* (LDS) vector
#define DOT4_V(Wv, hv) \
    a0 = fmaf(Wv.x, (hv).x, a0); \
    a1 = fmaf(Wv.y, (hv).y, a1); \
    a2 = fmaf(Wv.z, (hv).z, a2); \
    a3 = fmaf(Wv.w, (hv).w, a3);
#define DOT64_V(h4) \
    DOT4_V(W00, (h4)[0])  DOT4_V(W01, (h4)[1])  DOT4_V(W02, (h4)[2])  DOT4_V(W03, (h4)[3])  \
    DOT4_V(W04, (h4)[4])  DOT4_V(W05, (h4)[5])  DOT4_V(W06, (h4)[6])  DOT4_V(W07, (h4)[7])  \
    DOT4_V(W08, (h4)[8])  DOT4_V(W09, (h4)[9])  DOT4_V(W10, (h4)[10]) DOT4_V(W11, (h4)[11]) \
    DOT4_V(W12, (h4)[12]) DOT4_V(W13, (h4)[13]) DOT4_V(W14, (h4)[14]) DOT4_V(W15, (h4)[15])

// ---------------------------------------------------------------------------
// Kernel 1: xp[b][t][m*64+d] = Xb[m][d] + sum_k XW[m][d][k] * x_m[b][t][k]
// ---------------------------------------------------------------------------
__global__ __launch_bounds__(256, 2)
void k1_xproj(const float* __restrict__ xa, const float* __restrict__ xv,
              const float* __restrict__ xl, const float* __restrict__ XW,
              const float* __restrict__ Xb, float* __restrict__ xp)
{
    const int m  = blockIdx.z;
    const int b  = blockIdx.y;
    const int t0 = blockIdx.x * 128;
    const float* __restrict__ xm = (m == 0) ? xa : ((m == 1) ? xv : xl);
    const int tid = threadIdx.x;
    const int q = tid >> 6;
    const int d = tid & 63;

    __shared__ __align__(16) float xs[4][256];
    __shared__ float part[4][4][64];

    const float4* wsrc = reinterpret_cast<const float4*>(XW + ((m * 64 + d) * 256 + q * 64));
    DECL_W16(wsrc);
    const float xbv = Xb[m * 64 + d];

    for (int g = 0; g < 32; ++g) {
        const int tb = t0 + g * 4;
        {
            const float* src = xm + ((size_t)b * S_ + tb) * D_;
            xs[0][tid] = src[0 * 256 + tid];
            xs[1][tid] = src[1 * 256 + tid];
            xs[2][tid] = src[2 * 256 + tid];
            xs[3][tid] = src[3 * 256 + tid];
        }
        __syncthreads();
        #pragma unroll
        for (int tt = 0; tt < 4; ++tt) {
            const float4* xq = reinterpret_cast<const float4*>(&xs[tt][q * 64]);
            float a0 = 0.f, a1 = 0.f, a2 = 0.f, a3 = 0.f;
            DOT64_V(xq);
            part[tt][q][d] = (a0 + a1) + (a2 + a3);
        }
        __syncthreads();
        {
            const int tt = q;
            float ssum = part[tt][0][d] + part[tt][1][d] + part[tt][2][d] + part[tt][3][d] + xbv;
            xp[((size_t)b * S_ + tb + tt) * MD_ + m * 64 + d] = ssum;
        }
    }
}

// ---------------------------------------------------------------------------
// Kernel 2 v3: recurrence. 32 blocks x 768 threads (12 waves).
//   waves 0..8  (w=m*3+s): part[m][s][d] = Wrow(64) . h_s(64), weights in
//               16 NAMED float4 registers (the R2 array went to scratch).
//   waves 9..11: gate partials (W1 rows), then parallel tail: each gate wave
//               computes all 64 z=tanh(...) (one per lane), its 3 W2-rows via
//               shfl_xor butterflies, softmax of its attn row -> LDS.
//   owners combine + silu + double-buffered h. 3 lgkm-only barriers/step.
// ---------------------------------------------------------------------------
__global__ __launch_bounds__(768, 1)
void k2_recur(const float* __restrict__ xp, float* __restrict__ hbuf,
              const float* __restrict__ HW, const float* __restrict__ Hb,
              const float* __restrict__ CW, const float* __restrict__ W1,
              const float* __restrict__ b1, const float* __restrict__ W2,
              const float* __restrict__ b2)
{
    const int b    = blockIdx.x;
    const int tid  = threadIdx.x;
    const int w    = tid >> 6;
    const int lane = tid & 63;

    const bool is_su    = (w < 9);
    const int  m        = is_su ? (w / 3) : 0;
    const int  s        = is_su ? (w % 3) : (w - 9);   // su: src seg; gate: seg g
    const bool is_owner = is_su && (s == m);
    const bool is_gate  = !is_su;
    const int  g        = w - 9;                        // gate row (valid if gate)

    __shared__ __align__(16) float hds[2][MD_];
    __shared__ float parts[12][64];
    __shared__ float attnsh[9];

    if (tid < MD_) hds[0][tid] = 0.f;

    // ---- weights: 16 named float4 registers per lane ----
    const float* base;
    if (is_su) base = (s == m) ? (HW + (m * 64 + lane) * 64)
                               : (CW + (((m * 3 + s) * 64) + lane) * 64);
    else       base = W1 + lane * MD_ + s * 64;
    const float4* wsrc = reinterpret_cast<const float4*>(base);
    DECL_W16(wsrc);

    const float hbv = is_owner ? Hb[m * 64 + lane] : 0.f;
    const float b1v = is_gate  ? b1[lane] : 0.f;
    // gate wave g owns W2 rows 3g..3g+2; lane holds column `lane` of each
    float w2r0 = 0.f, w2r1 = 0.f, w2r2 = 0.f, b2v0 = 0.f, b2v1 = 0.f, b2v2 = 0.f;
    if (is_gate) {
        w2r0 = W2[(g * 3 + 0) * 64 + lane];
        w2r1 = W2[(g * 3 + 1) * 64 + lane];
        w2r2 = W2[(g * 3 + 2) * 64 + lane];
        b2v0 = b2[g * 3 + 0]; b2v1 = b2[g * 3 + 1]; b2v2 = b2[g * 3 + 2];
    }

    const int s1 = (m + 1) % 3, s2 = (m + 2) % 3;

    float xnext = is_owner ? xp[((size_t)b * S_) * MD_ + m * 64 + lane] : 0.f;
    float hist0 = 0.f, hist1 = 0.f, hist2 = 0.f, hist3 = 0.f;

    __syncthreads();

    for (int t = 0; t < S_; ++t) {
        const int cur = t & 1, nxt = cur ^ 1;
        const float xv = xnext;
        if (is_owner && (t + 1 < S_))
            xnext = xp[((size_t)b * S_ + t + 1) * MD_ + m * 64 + lane];

        // ---- phase A: every wave one 64-long dot, weights in registers ----
        float hreg = hds[cur][s * 64 + lane];
        float a0 = 0.f, a1 = 0.f, a2 = 0.f, a3 = 0.f;
        DOT64_RL();
        const float acc = (a0 + a1) + (a2 + a3);
        parts[w][lane] = acc;
        BAR_LGKM();   // partials visible

        // ---- gate tail: 3 gate waves in parallel ----
        if (is_gate) {
            float z = tanhf(b1v + parts[9][lane] + parts[10][lane] + parts[11][lane]);
            float p0 = w2r0 * z, p1 = w2r1 * z, p2 = w2r2 * z;
            #pragma unroll
            for (int off = 32; off >= 1; off >>= 1) {
                p0 += __shfl_xor(p0, off);
                p1 += __shfl_xor(p1, off);
                p2 += __shfl_xor(p2, off);
            }
            float r0 = p0 + b2v0, r1 = p1 + b2v1, r2 = p2 + b2v2;
            float mx = fmaxf(r0, fmaxf(r1, r2));
            float e0 = expf(r0 - mx), e1 = expf(r1 - mx), e2 = expf(r2 - mx);
            float inv = 1.f / (e0 + e1 + e2);
            if (lane == 0) {
                attnsh[g * 3 + 0] = e0 * inv;
                attnsh[g * 3 + 1] = e1 * inv;
                attnsh[g * 3 + 2] = e2 * inv;
            }
        }
        BAR_LGKM();   // attn visible

        // ---- owner combine + state update ----
        if (is_owner) {
            float p1  = parts[m * 3 + s1][lane];
            float p2  = parts[m * 3 + s2][lane];
            float a1v = attnsh[m * 3 + s1];
            float a2v = attnsh[m * 3 + s2];
            float suv = xv + hbv + acc + a1v * p1 + a2v * p2;
            float hn  = suv / (1.f + expf(-suv));
            hds[nxt][m * 64 + lane] = hn;
            if      ((t & 3) == 0) hist0 = hn;
            else if ((t & 3) == 1) hist1 = hn;
            else if ((t & 3) == 2) hist2 = hn;
            else {
                hist3 = hn;
                float* dst = hbuf + ((size_t)b * S_ + (t - 3)) * MD_ + m * 64 + lane;
                dst[0 * MD_] = hist0; dst[1 * MD_] = hist1;
                dst[2 * MD_] = hist2; dst[3 * MD_] = hist3;
            }
        }
        BAR_LGKM();   // h_new visible
    }
}

// ---------------------------------------------------------------------------
// Kernel 3: out = LayerNorm(Ob + OW@h + x); OW row in NAMED registers.
// ---------------------------------------------------------------------------
__global__ __launch_bounds__(256, 2)
void k3_out(const float* __restrict__ xa, const float* __restrict__ xv,
            const float* __restrict__ xl, const float* __restrict__ hbuf,
            const float* __restrict__ OW, const float* __restrict__ Ob,
            const float* __restrict__ lng, const float* __restrict__ lnb,
            float* __restrict__ out)
{
    const int m  = blockIdx.z;
    const int b  = blockIdx.y;
    const int t0 = blockIdx.x * 128;
    const float* __restrict__ xm = (m == 0) ? xa : ((m == 1) ? xv : xl);
    const int k    = threadIdx.x;
    const int wv   = k >> 6;
    const int lane = k & 63;

    __shared__ __align__(16) float hs[4 * 64];
    __shared__ float psum[16], qsum[16];

    const float4* wsrc = reinterpret_cast<const float4*>(OW + (m * D_ + k) * DS_);
    DECL_W16(wsrc);
    const float obv = Ob[m * D_ + k];
    const float gv  = lng[m * D_ + k];
    const float bv  = lnb[m * D_ + k];

    for (int gg = 0; gg < 32; ++gg) {
        const int tb = t0 + gg * 4;
        hs[k] = hbuf[((size_t)b * S_ + tb + (k >> 6)) * MD_ + m * 64 + (k & 63)];
        __syncthreads();

        float v0, v1, v2, v3;
        {
            const float4* h4 = reinterpret_cast<const float4*>(&hs[0]);
            float a0 = 0.f, a1 = 0.f, a2 = 0.f, a3 = 0.f;
            DOT64_V(h4);
            v0 = obv + (a0 + a1) + (a2 + a3) + xm[((size_t)b * S_ + tb + 0) * D_ + k];
        }
        {
            const float4* h4 = reinterpret_cast<const float4*>(&hs[64]);
            float a0 = 0.f, a1 = 0.f, a2 = 0.f, a3 = 0.f;
            DOT64_V(h4);
            v1 = obv + (a0 + a1) + (a2 + a3) + xm[((size_t)b * S_ + tb + 1) * D_ + k];
        }
        {
            const float4* h4 = reinterpret_cast<const float4*>(&hs[128]);
            float a0 = 0.f, a1 = 0.f, a2 = 0.f, a3 = 0.f;
            DOT64_V(h4);
            v2 = obv + (a0 + a1) + (a2 + a3) + xm[((size_t)b * S_ + tb + 2) * D_ + k];
        }
        {
            const float4* h4 = reinterpret_cast<const float4*>(&hs[192]);
            float a0 = 0.f, a1 = 0.f, a2 = 0.f, a3 = 0.f;
            DOT64_V(h4);
            v3 = obv + (a0 + a1) + (a2 + a3) + xm[((size_t)b * S_ + tb + 3) * D_ + k];
        }

        float s0 = v0, s1v = v1, s2v = v2, s3 = v3;
        float q0 = v0 * v0, q1 = v1 * v1, q2 = v2 * v2, q3 = v3 * v3;
        #pragma unroll
        for (int off = 32; off >= 1; off >>= 1) {
            s0  += __shfl_down(s0, off);  s1v += __shfl_down(s1v, off);
            s2v += __shfl_down(s2v, off); s3  += __shfl_down(s3, off);
            q0  += __shfl_down(q0, off);  q1  += __shfl_down(q1, off);
            q2  += __shfl_down(q2, off);  q3  += __shfl_down(q3, off);
        }
        if (lane == 0) {
            psum[wv * 4 + 0] = s0;  psum[wv * 4 + 1] = s1v;
            psum[wv * 4 + 2] = s2v; psum[wv * 4 + 3] = s3;
            qsum[wv * 4 + 0] = q0;  qsum[wv * 4 + 1] = q1;
            qsum[wv * 4 + 2] = q2;  qsum[wv * 4 + 3] = q3;
        }
        __syncthreads();

        const size_t obase = (size_t)m * ((size_t)B_ * S_ * D_) + ((size_t)b * S_ + tb) * D_ + k;
        {
            float ss = psum[0] + psum[4] + psum[8] + psum[12];
            float qq = qsum[0] + qsum[4] + qsum[8] + qsum[12];
            float mu = ss * (1.f / 256.f);
            float var = qq * (1.f / 256.f) - mu * mu;
            float rs = rsqrtf(var + 1e-5f);
            out[obase + 0 * D_] = (v0 - mu) * rs * gv + bv;
        }
        {
            float ss = psum[1] + psum[5] + psum[9] + psum[13];
            float qq = qsum[1] + qsum[5] + qsum[9] + qsum[13];
            float mu = ss * (1.f / 256.f);
            float var = qq * (1.f / 256.f) - mu * mu;
            float rs = rsqrtf(var + 1e-5f);
            out[obase + 1 * D_] = (v1 - mu) * rs * gv + bv;
        }
        {
            float ss = psum[2] + psum[6] + psum[10] + psum[14];
            float qq = qsum[2] + qsum[6] + qsum[10] + qsum[14];
            float mu = ss * (1.f / 256.f);
            float var = qq * (1.f / 256.f) - mu * mu;
            float rs = rsqrtf(var + 1e-5f);
            out[obase + 2 * D_] = (v2 - mu) * rs * gv + bv;
        }
        {
            float ss = psum[3] + psum[7] + psum[11] + psum[15];
            float qq = qsum[3] + qsum[7] + qsum[11] + qsum[15];
            float mu = ss * (1.f / 256.f);
            float var = qq * (1.f / 256.f) - mu * mu;
            float rs = rsqrtf(var + 1e-5f);
            out[obase + 3 * D_] = (v3 - mu) * rs * gv + bv;
        }
    }
}

extern "C" void kernel_launch(void* const* d_in, const int* in_sizes, int n_in,
                              void* d_out, int out_size, void* d_ws, size_t ws_size,
                              hipStream_t stream)
{
    const float* xa  = (const float*)d_in[0];
    const float* xv  = (const float*)d_in[1];
    const float* xl  = (const float*)d_in[2];
    const float* XW  = (const float*)d_in[3];
    const float* Xb  = (const float*)d_in[4];
    const float* HW  = (const float*)d_in[5];
    const float* Hb  = (const float*)d_in[6];
    const float* OW  = (const float*)d_in[7];
    const float* Ob  = (const float*)d_in[8];
    const float* CW  = (const float*)d_in[9];
    const float* W1  = (const float*)d_in[10];
    const float* b1  = (const float*)d_in[11];
    const float* W2  = (const float*)d_in[12];
    const float* b2  = (const float*)d_in[13];
    const float* lng = (const float*)d_in[14];
    const float* lnb = (const float*)d_in[15];
    float* out = (float*)d_out;

    float* xp = (float*)d_ws;                          // [B][S][192]
    float* hb = xp + (size_t)B_ * S_ * MD_;            // [B][S][192]

    k1_xproj<<<dim3(8, 32, 3), 256, 0, stream>>>(xa, xv, xl, XW, Xb, xp);
    k2_recur<<<dim3(32), 768, 0, stream>>>(xp, hb, HW, Hb, CW, W1, b1, W2, b2);
    k3_out  <<<dim3(8, 32, 3), 256, 0, stream>>>(xa, xv, xl, hb, OW, Ob, lng, lnb, out);
}